// Round 12
// baseline (154.215 us; speedup 1.0000x reference)
//
#include <hip/hip_runtime.h>
#include <stdint.h>
#include <math.h>

typedef unsigned long long u64;
typedef uint32_t u32;

#define BATCH   262144
#define DIM     120
#define NBLK0   1024      // k0: 256 rows per block (1 row/thread)
#define NBLK1   2048      // k1b/k2: 128 rows per block
#define NPART   4096      // partial slots per column (2 halves * 2048 blocks)
#define CH      8         // k3: columns per register chunk
#define NBLK3   1024      // k3 blocks (256 rows each)

// Bit layout (x and w MUST match): element c -> word (c>>6), bit (c&63).
// word0 = cols 0..63, word1 = cols 64..119 (56 bits used).

// ---------------- workspace layout (bytes) ----------------
#define WS_XBITS   0              // u64[BATCH*4]            8,388,608
#define WS_WBITS   8388608        // u64[128*4]
#define WS_META    8393216        // u32[256]
#define WS_HS      8394240        // u32[120*4096]
#define WS_HS2     10360320      // u32[120*4096]
#define WS_SS      12326400      // f32[120*4096]
#define WS_SS2     14292480      // f32[120*4096]
#define WS_BN2C    16258560      // f32[256]
#define WS_OQ      16259584      // u32[BATCH]
#define WS_OACC    17308160      // u32 yflag @ word 8
#define WS_OP      17308224      // u32[1024*4]
#define WS_TOTAL   17324624

// Per-thread row pack: 30 independent float4 loads -> deep ILP, no ballots.
__device__ __forceinline__ void pack_row(const float* __restrict__ r,
                                         u64& p0, u64& p1, u64& z0, u64& z1) {
    p0 = 0; p1 = 0; z0 = 0; z1 = 0;
    #pragma unroll
    for (int i = 0; i < 30; ++i) {
        float4 v = *(const float4*)(r + i * 4);
        int c = i * 4;
        #pragma unroll
        for (int k = 0; k < 4; ++k) {
            float f = (k == 0) ? v.x : (k == 1) ? v.y : (k == 2) ? v.z : v.w;
            int cc = c + k;
            u64 bp = (f > 0.f) ? 1ull : 0ull;
            u64 bz = (f == 0.f) ? 1ull : 0ull;
            if (cc < 64) { p0 |= bp << cc;        z0 |= bz << cc; }
            else         { p1 |= bp << (cc - 64); z1 |= bz << (cc - 64); }
        }
    }
}

__device__ __forceinline__ u32 hq_from_bits(u64 p0, u64 p1, u64 z0, u64 z1,
                                            u64 q0, u64 q1, u64 y0, u64 y1,
                                            bool hasY, bool hasZ) {
    u32 hq = (u32)(__popcll(p0 & q0) + __popcll(p1 & q1)) << 2;
    if (hasY)
        hq += 2u * (u32)(__popcll(p0 & y0) + __popcll(p1 & y1))
            + (u32)(__popcll(z0 & y0) + __popcll(z1 & y1));
    if (hasZ)
        hq += 2u * (u32)(__popcll(z0 & q0) + __popcll(z1 & q1));
    return hq;   // == 4 * h, exact integer in [0, 480]
}

__device__ __forceinline__ void proc_col(u64 p0, u64 p1, u64 q0, u64 q1,
                                         u64 mw, u32& oq) {
    u32 hq = ((u32)(__popcll(p0 & q0) + __popcll(p1 & q1))) << 2;
    u32 m  = (u32)mw;
    u32 lw = (u32)(mw >> 32);
    u32 ge = (u32)(hq >= (m & 511u)) + (u32)(hq >= ((m >> 9) & 511u));
    u32 hb2 = (m & (1u << 18)) ? 2u - ge : ge;
    oq += hb2 * lw;
}

// K0: pure streaming pack. Thread <-> row. No LDS, no sync, no ballots.
__global__ __launch_bounds__(256) void k0_pack(
        const float* __restrict__ x, u64* __restrict__ xbits) {
    size_t row = (size_t)blockIdx.x * 256 + threadIdx.x;
    u64 p0, p1, z0, z1;
    pack_row(x + row * DIM, p0, p1, z0, z1);
    ulonglong2* dst = (ulonglong2*)(xbits + row * 4);
    dst[0] = make_ulonglong2(p0, p1);
    dst[1] = make_ulonglong2(z0, z1);
}

// K1b: integer h-stats. Stages 128 rows of xbits in LDS; packs conv_w
// per-thread per-block (L2-hot, ILP30); block 0 publishes wbits + yflag.
__global__ __launch_bounds__(256) void k1b_hstats(
        const u64* __restrict__ xbits, const float* __restrict__ w,
        u64* __restrict__ wbits, u32* __restrict__ oacc,
        u32* __restrict__ hP, u32* __restrict__ h2P) {
    __shared__ __align__(16) u64 lb[128][4];
    __shared__ __align__(16) u64 sw[128][4];
    __shared__ u32 swf[4];
    int tid = threadIdx.x, bid = blockIdx.x;

    ((ulonglong2*)&lb[0][0])[tid] =
        ((const ulonglong2*)(xbits + (size_t)bid * 512))[tid];

    u64 q0 = 0, q1 = 0, y0w = 0, y1w = 0;
    if (tid < DIM) pack_row(w + (size_t)tid * DIM, q0, q1, y0w, y1w);
    if (tid < 128) {
        sw[tid][0] = q0; sw[tid][1] = q1; sw[tid][2] = y0w; sw[tid][3] = y1w;
    }
    {   // block-wide "any conv_w zero" flag via per-wave ballots
        u64 bal = __ballot((y0w | y1w) != 0);
        if ((tid & 63) == 0) swf[tid >> 6] = (bal != 0) ? 1u : 0u;
    }
    __syncthreads();

    if (bid == 0) {
        ((u64*)wbits)[tid]       = ((const u64*)sw)[tid];
        ((u64*)wbits)[tid + 256] = ((const u64*)sw)[tid + 256];
        if (tid == 0) oacc[8] = (swf[0] | swf[1] | swf[2] | swf[3]) ? 1u : 0u;
    }

    int j = tid & 127, half = tid >> 7;
    if (j < DIM) {
        u64 wq0 = sw[j][0], wq1 = sw[j][1], wy0 = sw[j][2], wy1 = sw[j][3];
        bool hasY = (wy0 | wy1) != 0;
        u32 SA = 0, S2A = 0, SB = 0, S2B = 0;
        int r0 = half * 64;
        for (int r = r0; r < r0 + 64; r += 2) {
            ulonglong2 a0 = *(const ulonglong2*)&lb[r][0];
            ulonglong2 a1 = *(const ulonglong2*)&lb[r][2];
            ulonglong2 b0 = *(const ulonglong2*)&lb[r+1][0];
            ulonglong2 b1 = *(const ulonglong2*)&lb[r+1][2];
            u32 hqa = hq_from_bits(a0.x, a0.y, a1.x, a1.y,
                                   wq0, wq1, wy0, wy1, hasY, (a1.x | a1.y) != 0);
            u32 hqb = hq_from_bits(b0.x, b0.y, b1.x, b1.y,
                                   wq0, wq1, wy0, wy1, hasY, (b1.x | b1.y) != 0);
            SA += hqa; S2A += hqa * hqa;
            SB += hqb; S2B += hqb * hqb;
        }
        int pidx = j * NPART + bid * 2 + half;
        hP[pidx] = SA + SB; h2P[pidx] = S2A + S2B;
    }
}

// R1: reduce integer h-stats -> fold BN2 into  z = fma(hq, c1q, c0)
__global__ __launch_bounds__(256) void r1_hreduce(
        const u32* __restrict__ hP, const u32* __restrict__ h2P,
        const float* __restrict__ g2, const float* __restrict__ b2,
        float* __restrict__ bn2c) {
    int j = blockIdx.x, tid = threadIdx.x;
    u32 s = 0; u64 s2 = 0;
    for (int k = tid; k < NPART; k += 256) { s += hP[j*NPART+k]; s2 += (u64)h2P[j*NPART+k]; }
    for (int off = 32; off; off >>= 1) { s += __shfl_down(s, off, 64); s2 += __shfl_down(s2, off, 64); }
    __shared__ u32 as_[4]; __shared__ u64 as2_[4];
    int lane = tid & 63, wave = tid >> 6;
    if (lane == 0) { as_[wave] = s; as2_[wave] = s2; }
    __syncthreads();
    if (tid == 0) {
        u32 S = as_[0] + as_[1] + as_[2] + as_[3];
        u64 S2 = as2_[0] + as2_[1] + as2_[2] + as2_[3];
        double m2 = (double)S * 0.25 / (double)BATCH;
        double e2 = (double)S2 * 0.0625 / (double)BATCH;
        double v2 = e2 - m2 * m2;
        float rs = (float)(1.0 / sqrt(v2 + 1e-5));
        float c1 = rs * g2[j];
        float c0 = fmaf(-(float)m2, c1, b2[j]);
        bn2c[j] = c1 * 0.25f; bn2c[128 + j] = c0;
    }
}

// K2: stage bits in LDS, recompute hq, softsign stats (dual f32 accumulators)
__global__ __launch_bounds__(256) void k2_sstats(
        const u64* __restrict__ xbits, const u64* __restrict__ wbits,
        const float* __restrict__ bn2c,
        float* __restrict__ sS, float* __restrict__ sS2) {
    __shared__ u64 lb[128][4];
    int tid = threadIdx.x;
    ((ulonglong2*)&lb[0][0])[tid] =
        ((const ulonglong2*)(xbits + (size_t)blockIdx.x * 512))[tid];
    __syncthreads();
    int j = tid & 127, half = tid >> 7;
    if (j >= DIM) return;
    u64 q0 = wbits[j*4+0], q1 = wbits[j*4+1], y0 = wbits[j*4+2], y1 = wbits[j*4+3];
    bool hasY = (y0 | y1) != 0;
    float c1q = bn2c[j], c0 = bn2c[128 + j];
    float SsA = 0.f, Ss2A = 0.f, SsB = 0.f, Ss2B = 0.f;
    int r0 = half * 64;
    for (int r = r0; r < r0 + 64; r += 2) {
        u64 z0 = lb[r][2], z1 = lb[r][3];
        u32 hqa = hq_from_bits(lb[r][0], lb[r][1], z0, z1,
                               q0, q1, y0, y1, hasY, (z0 | z1) != 0);
        u64 w0 = lb[r+1][2], w1 = lb[r+1][3];
        u32 hqb = hq_from_bits(lb[r+1][0], lb[r+1][1], w0, w1,
                               q0, q1, y0, y1, hasY, (w0 | w1) != 0);
        float za = fmaf((float)hqa, c1q, c0);
        float sa = za * __builtin_amdgcn_rcpf(1.f + fabsf(za));
        SsA += sa; Ss2A = fmaf(sa, sa, Ss2A);
        float zb = fmaf((float)hqb, c1q, c0);
        float sb = zb * __builtin_amdgcn_rcpf(1.f + fabsf(zb));
        SsB += sb; Ss2B = fmaf(sb, sb, Ss2B);
    }
    int pidx = j * NPART + blockIdx.x * 2 + half;
    sS[pidx] = SsA + SsB; sS2[pidx] = Ss2A + Ss2B;
}

// R2: reduce softsign stats (f64), fold BN1, derive the two integer
// thresholds per column; lin_w binarize computed inline.
__global__ __launch_bounds__(256) void r2_sreduce(
        const float* __restrict__ sS, const float* __restrict__ sS2,
        const float* __restrict__ g1, const float* __restrict__ b1,
        const float* __restrict__ bn2c, const float* __restrict__ lw,
        u32* __restrict__ meta) {
    int j = blockIdx.x, tid = threadIdx.x;
    double s = 0.0, s2 = 0.0;
    for (int k = tid; k < NPART; k += 256) { s += (double)sS[j*NPART+k]; s2 += (double)sS2[j*NPART+k]; }
    for (int off = 32; off; off >>= 1) { s += __shfl_down(s, off, 64); s2 += __shfl_down(s2, off, 64); }
    __shared__ double ds_[4], ds2_[4];
    __shared__ float sd1, sd0;
    __shared__ u32 cnt[3];
    __shared__ u32 sfirst, slast;
    int lane = tid & 63, wave = tid >> 6;
    if (lane == 0) { ds_[wave] = s; ds2_[wave] = s2; }
    if (tid < 3) cnt[tid] = 0;
    __syncthreads();
    if (tid == 0) {
        double S = ds_[0] + ds_[1] + ds_[2] + ds_[3];
        double S2 = ds2_[0] + ds2_[1] + ds2_[2] + ds2_[3];
        double m1 = S / (double)BATCH;
        double v1 = S2 / (double)BATCH - m1 * m1;
        float rs = (float)(1.0 / sqrt(v1 + 1e-5));
        float d1 = rs * g1[j];
        float d0 = fmaf(-(float)m1, d1, b1[j]);
        sd1 = d1; sd0 = d0;
    }
    __syncthreads();
    float c1q = bn2c[j], c0 = bn2c[128 + j];
    float d1 = sd1, d0 = sd0;
    for (int hq = tid; hq < 481; hq += 256) {
        float z = fmaf((float)hq, c1q, c0);
        float sv = z * __builtin_amdgcn_rcpf(1.f + fabsf(z));
        float h1 = fmaf(sv, d1, d0);
        u32 hb2 = h1 > 0.f ? 2u : (h1 == 0.f ? 1u : 0u);
        atomicAdd(&cnt[hb2], 1u);
        if (hq == 0)   sfirst = hb2;
        if (hq == 480) slast  = hb2;
    }
    __syncthreads();
    if (tid == 0) {
        u32 n0 = cnt[0], n1 = cnt[1], n2 = cnt[2];
        u32 dec = (slast < sfirst) ? 1u : 0u;
        u32 A = dec ? n2 : n0;
        u32 B = A + n1;
        float w0 = lw[j], w1 = lw[DIM + j];
        u32 l0 = w0 > 0.f ? 2u : (w0 == 0.f ? 1u : 0u);
        u32 l1 = w1 > 0.f ? 2u : (w1 == 0.f ? 1u : 0u);
        meta[2*j]   = A | (B << 9) | (dec << 18);
        meta[2*j+1] = l0 | (l1 << 16);
    }
}

// K3: thread <-> row, chunked-register column loop, per-block stat partials
// to distinct addresses (no global atomics).
__global__ __launch_bounds__(256) void k3_out(
        const u64* __restrict__ xbits, const u64* __restrict__ wbits,
        const u32* __restrict__ meta, const u32* __restrict__ oacc,
        u32* __restrict__ oqbuf, u32* __restrict__ oP) {
    __shared__ u64 sq0[DIM], sq1[DIM], smw[DIM], sy0[DIM], sy1[DIM];
    int tid = threadIdx.x;
    for (int k = tid; k < DIM; k += 256) {
        sq0[k] = wbits[k*4+0]; sq1[k] = wbits[k*4+1];
        sy0[k] = wbits[k*4+2]; sy1[k] = wbits[k*4+3];
        smw[k] = (u64)meta[2*k] | ((u64)meta[2*k+1] << 32);
    }
    __syncthreads();
    size_t row = (size_t)blockIdx.x * 256 + tid;
    const ulonglong2* xb = (const ulonglong2*)xbits;
    ulonglong2 rp = xb[row*2], rz = xb[row*2+1];
    u64 p0 = rp.x, p1 = rp.y, z0 = rz.x, z1 = rz.y;
    u32 oq = 0;
    for (int c = 0; c < DIM; c += CH) {
        ulonglong2 A[CH/2], B[CH/2], Mw[CH/2];
        #pragma unroll
        for (int t = 0; t < CH/2; ++t) {
            A[t] = *(const ulonglong2*)&sq0[c + 2*t];
            B[t] = *(const ulonglong2*)&sq1[c + 2*t];
            Mw[t] = *(const ulonglong2*)&smw[c + 2*t];
        }
        #pragma unroll
        for (int t = 0; t < CH/2; ++t) {
            proc_col(p0, p1, A[t].x, B[t].x, Mw[t].x, oq);
            proc_col(p0, p1, A[t].y, B[t].y, Mw[t].y, oq);
        }
    }
    bool slow = (oacc[8] != 0) | ((z0 | z1) != 0);
    if (__any(slow)) {
        if (slow) {          // exact full recompute (expected ~2 rows/batch)
            oq = 0;
            for (int j = 0; j < DIM; ++j) {
                u64 y0 = sy0[j], y1 = sy1[j];
                u32 hq = hq_from_bits(p0, p1, z0, z1, sq0[j], sq1[j], y0, y1,
                                      (y0 | y1) != 0, (z0 | z1) != 0);
                u64 mw = smw[j];
                u32 m = (u32)mw, lw = (u32)(mw >> 32);
                u32 ge = (u32)(hq >= (m & 511u)) + (u32)(hq >= ((m >> 9) & 511u));
                oq += ((m & (1u << 18)) ? 2u - ge : ge) * lw;
            }
        }
    }
    oqbuf[row] = oq;
    u32 o0 = oq & 0xffffu, o1 = oq >> 16;
    u32 a = o0, b = o1, c2 = o0 * o0, d2 = o1 * o1;
    for (int off = 32; off; off >>= 1) {
        a += __shfl_down(a, off, 64);  b += __shfl_down(b, off, 64);
        c2 += __shfl_down(c2, off, 64); d2 += __shfl_down(d2, off, 64);
    }
    __shared__ u32 r0_[4], r1_[4], r2_[4], r3_[4];
    int lane = tid & 63, wv = tid >> 6;
    if (lane == 0) { r0_[wv] = a; r1_[wv] = b; r2_[wv] = c2; r3_[wv] = d2; }
    __syncthreads();
    if (tid == 0) {
        u32* dst = oP + (size_t)blockIdx.x * 4;
        dst[0] = r0_[0] + r0_[1] + r0_[2] + r0_[3];
        dst[1] = r1_[0] + r1_[1] + r1_[2] + r1_[3];
        dst[2] = r2_[0] + r2_[1] + r2_[2] + r2_[3];
        dst[3] = r3_[0] + r3_[1] + r3_[2] + r3_[3];
    }
}

// K4: each block redundantly reduces the 16KB oP partials (exact integers,
// f64 finalize), then normalizes its 256 rows + 2-class log_softmax.
__global__ __launch_bounds__(256) void k4_final(
        const u32* __restrict__ oqbuf, const u32* __restrict__ oP,
        float* __restrict__ out) {
    int tid = threadIdx.x;
    u64 a = 0, b = 0, c2 = 0, d2 = 0;
    for (int k = tid; k < NBLK3; k += 256) {
        uint4 p = ((const uint4*)oP)[k];
        a += p.x; b += p.y; c2 += p.z; d2 += p.w;
    }
    for (int off = 32; off; off >>= 1) {
        a += __shfl_down(a, off, 64);  b += __shfl_down(b, off, 64);
        c2 += __shfl_down(c2, off, 64); d2 += __shfl_down(d2, off, 64);
    }
    __shared__ u64 s0_[4], s1_[4], s2_[4], s3_[4];
    __shared__ float sfin[4];
    int lane = tid & 63, wv = tid >> 6;
    if (lane == 0) { s0_[wv] = a; s1_[wv] = b; s2_[wv] = c2; s3_[wv] = d2; }
    __syncthreads();
    if (tid < 2) {
        u64 S  = (tid == 0) ? s0_[0]+s0_[1]+s0_[2]+s0_[3] : s1_[0]+s1_[1]+s1_[2]+s1_[3];
        u64 S2 = (tid == 0) ? s2_[0]+s2_[1]+s2_[2]+s2_[3] : s3_[0]+s3_[1]+s3_[2]+s3_[3];
        double av = (double)S * 0.25 / (double)BATCH;
        double e2 = (double)S2 * 0.0625 / (double)BATCH;
        double vo = e2 - av * av;
        sfin[tid]     = (float)av;
        sfin[2 + tid] = (float)(1.0 / sqrt(vo + 1e-5));
    }
    __syncthreads();
    size_t row = (size_t)blockIdx.x * 256 + tid;
    u32 v = oqbuf[row];
    float o0 = ((float)(v & 0xffffu) * 0.25f - sfin[0]) * sfin[2];
    float o1 = ((float)(v >> 16)     * 0.25f - sfin[1]) * sfin[3];
    float m = fmaxf(o0, o1);
    float l0 = o0 - m, l1 = o1 - m;
    float ls = logf(expf(l0) + expf(l1));
    ((float2*)out)[row] = make_float2(l0 - ls, l1 - ls);
}

extern "C" void kernel_launch(void* const* d_in, const int* in_sizes, int n_in,
                              void* d_out, int out_size, void* d_ws, size_t ws_size,
                              hipStream_t stream) {
    const float* x  = (const float*)d_in[0];
    const float* cw = (const float*)d_in[1];
    const float* g2 = (const float*)d_in[2];
    const float* b2 = (const float*)d_in[3];
    const float* g1 = (const float*)d_in[4];
    const float* b1 = (const float*)d_in[5];
    const float* lw = (const float*)d_in[6];
    // d_in[7] (lin_b) cancels through the final no-affine batchnorm
    float* out = (float*)d_out;
    if (ws_size < (size_t)WS_TOTAL) return;   // fail loudly via poisoned d_out

    char* ws = (char*)d_ws;
    u64* xbits = (u64*)(ws + WS_XBITS);
    u64* wbits = (u64*)(ws + WS_WBITS);
    u32* meta  = (u32*)(ws + WS_META);
    u32* hP    = (u32*)(ws + WS_HS);
    u32* h2P   = (u32*)(ws + WS_HS2);
    float* sP  = (float*)(ws + WS_SS);
    float* s2P = (float*)(ws + WS_SS2);
    float* bn2c = (float*)(ws + WS_BN2C);
    u32* oqbuf = (u32*)(ws + WS_OQ);
    u32* oacc  = (u32*)(ws + WS_OACC);
    u32* oP    = (u32*)(ws + WS_OP);

    k0_pack   <<<NBLK0, 256, 0, stream>>>(x, xbits);
    k1b_hstats<<<NBLK1, 256, 0, stream>>>(xbits, cw, wbits, oacc, hP, h2P);
    r1_hreduce<<<DIM, 256, 0, stream>>>(hP, h2P, g2, b2, bn2c);
    k2_sstats <<<NBLK1, 256, 0, stream>>>(xbits, wbits, bn2c, sP, s2P);
    r2_sreduce<<<DIM, 256, 0, stream>>>(sP, s2P, g1, b1, bn2c, lw, meta);
    k3_out    <<<NBLK3, 256, 0, stream>>>(xbits, wbits, meta, oacc, oqbuf, oP);
    k4_final  <<<NBLK3, 256, 0, stream>>>(oqbuf, oP, out);
}

// Round 13
// 119.921 us; speedup vs baseline: 1.2860x; 1.2860x over previous
//
#include <hip/hip_runtime.h>
#include <stdint.h>
#include <math.h>

typedef unsigned long long u64;
typedef uint32_t u32;

#define BATCH   262144
#define DIM     120
#define NBLKP   2048      // kp: 128 rows per block
#define NBLK1   2048      // k1b/k2: 128 rows per block
#define NPART   4096      // partial slots per column (2 halves * 2048 blocks)
#define CH      8         // k3: columns per register chunk
#define NBLK3   1024      // k3 blocks (256 rows each)

// Bit layout (x and w MUST match): element c -> plane (c&3), bit (c>>2).
// word0 = plane0 | plane1<<30 ; word1 = plane2 | plane3<<30 (60 bits used).

// ---------------- workspace layout (bytes) ----------------
#define WS_XBITS   0              // u64[BATCH*4]            8,388,608
#define WS_WBITS   8388608        // u64[128*4]
#define WS_META    8393216        // u32[256]
#define WS_HS      8394240        // u32[120*4096]
#define WS_HS2     10360320      // u32[120*4096]
#define WS_SS      12326400      // f32[120*4096]
#define WS_SS2     14292480      // f32[120*4096]
#define WS_BN2C    16258560      // f32[256]
#define WS_OQ      16259584      // u32[BATCH]
#define WS_OACC    17308160      // u32 yflag @ word 8
#define WS_OP      17308224      // u32[1024*4]
#define WS_TOTAL   17324624

__device__ __forceinline__ u32 hq_from_bits(u64 p0, u64 p1, u64 z0, u64 z1,
                                            u64 q0, u64 q1, u64 y0, u64 y1,
                                            bool hasY, bool hasZ) {
    u32 hq = (u32)(__popcll(p0 & q0) + __popcll(p1 & q1)) << 2;
    if (hasY)
        hq += 2u * (u32)(__popcll(p0 & y0) + __popcll(p1 & y1))
            + (u32)(__popcll(z0 & y0) + __popcll(z1 & y1));
    if (hasZ)
        hq += 2u * (u32)(__popcll(z0 & q0) + __popcll(z1 & q1));
    return hq;   // == 4 * h, exact integer in [0, 480]
}

__device__ __forceinline__ void proc_col(u64 p0, u64 p1, u64 q0, u64 q1,
                                         u64 mw, u32& oq) {
    u32 hq = ((u32)(__popcll(p0 & q0) + __popcll(p1 & q1))) << 2;
    u32 m  = (u32)mw;
    u32 lw = (u32)(mw >> 32);
    u32 ge = (u32)(hq >= (m & 511u)) + (u32)(hq >= ((m >> 9) & 511u));
    u32 hb2 = (m & (1u << 18)) ? 2u - ge : ge;
    oq += hb2 * lw;
}

// KP: pure ballot pack. No LDS, no syncthreads, no w. Each wave packs 2 rows
// per iteration (half-wave split), lane0/lane32 store 16B each. 8 blocks/CU.
__global__ __launch_bounds__(256) void kp_pack(
        const float* __restrict__ x, u64* __restrict__ xbits) {
    int tid = threadIdx.x, lane = tid & 63, wv = tid >> 6;
    int l = lane & 31, h = lane >> 5;
    size_t base = (size_t)blockIdx.x * 128;
    int rb = wv * 2 + h;               // 0..7
    const u64 M = 0x3FFFFFFFull;
    for (int it = 0; it < 16; ++it) {
        int r = it * 8 + rb;
        float4 v = make_float4(-1.f, -1.f, -1.f, -1.f);
        if (l < 30) v = *(const float4*)(x + (base + r) * (size_t)DIM + l * 4);
        u64 m0 = __ballot(v.x > 0.f), m1 = __ballot(v.y > 0.f);
        u64 m2 = __ballot(v.z > 0.f), m3 = __ballot(v.w > 0.f);
        u64 n0 = __ballot(v.x == 0.f), n1 = __ballot(v.y == 0.f);
        u64 n2 = __ballot(v.z == 0.f), n3 = __ballot(v.w == 0.f);
        if (l == 0) {                  // lane0 -> row (h=0), lane32 -> row (h=1)
            u32 sh = h ? 32 : 0;
            ulonglong2 pw = make_ulonglong2(
                ((m0 >> sh) & M) | (((m1 >> sh) & M) << 30),
                ((m2 >> sh) & M) | (((m3 >> sh) & M) << 30));
            ulonglong2 zw = make_ulonglong2(
                ((n0 >> sh) & M) | (((n1 >> sh) & M) << 30),
                ((n2 >> sh) & M) | (((n3 >> sh) & M) << 30));
            ulonglong2* dst = (ulonglong2*)(xbits + (base + r) * 4);
            dst[0] = pw; dst[1] = zw;
        }
    }
}

// K1b: integer h-stats. Stages 128 rows of xbits in LDS (1 b128/thread);
// conv_w packed PER-THREAD with 30 independent unrolled float4 loads (plane
// layout: float4 k -> plane bits k; identical to ballot layout). Block 0
// publishes wbits + yflag.
__global__ __launch_bounds__(256) void k1b_hstats(
        const u64* __restrict__ xbits, const float* __restrict__ w,
        u64* __restrict__ wbits, u32* __restrict__ oacc,
        u32* __restrict__ hP, u32* __restrict__ h2P) {
    __shared__ __align__(16) u64 lb[128][4];
    __shared__ __align__(16) u64 sw[128][4];
    __shared__ u32 swf[4];
    int tid = threadIdx.x, bid = blockIdx.x;

    ((ulonglong2*)&lb[0][0])[tid] =
        ((const ulonglong2*)(xbits + (size_t)bid * 512))[tid];

    u64 q0 = 0, q1 = 0, yy0 = 0, yy1 = 0;
    if (tid < DIM) {
        u32 pl0 = 0, pl1 = 0, pl2 = 0, pl3 = 0;
        u32 zl0 = 0, zl1 = 0, zl2 = 0, zl3 = 0;
        const float* row = w + (size_t)tid * DIM;
        #pragma unroll
        for (int k = 0; k < 30; ++k) {
            float4 v = *(const float4*)(row + k * 4);
            pl0 |= (u32)(v.x > 0.f) << k;  zl0 |= (u32)(v.x == 0.f) << k;
            pl1 |= (u32)(v.y > 0.f) << k;  zl1 |= (u32)(v.y == 0.f) << k;
            pl2 |= (u32)(v.z > 0.f) << k;  zl2 |= (u32)(v.z == 0.f) << k;
            pl3 |= (u32)(v.w > 0.f) << k;  zl3 |= (u32)(v.w == 0.f) << k;
        }
        q0  = (u64)pl0 | ((u64)pl1 << 30);  q1  = (u64)pl2 | ((u64)pl3 << 30);
        yy0 = (u64)zl0 | ((u64)zl1 << 30);  yy1 = (u64)zl2 | ((u64)zl3 << 30);
    }
    if (tid < 128) {
        sw[tid][0] = q0; sw[tid][1] = q1; sw[tid][2] = yy0; sw[tid][3] = yy1;
    }
    {
        u64 bal = __ballot((yy0 | yy1) != 0);
        if ((tid & 63) == 0) swf[tid >> 6] = (bal != 0) ? 1u : 0u;
    }
    __syncthreads();

    if (bid == 0) {
        ((u64*)wbits)[tid]       = ((const u64*)sw)[tid];
        ((u64*)wbits)[tid + 256] = ((const u64*)sw)[tid + 256];
        if (tid == 0) oacc[8] = (swf[0] | swf[1] | swf[2] | swf[3]) ? 1u : 0u;
    }

    int j = tid & 127, half = tid >> 7;
    if (j < DIM) {
        u64 wq0 = sw[j][0], wq1 = sw[j][1], wy0 = sw[j][2], wy1 = sw[j][3];
        bool hasY = (wy0 | wy1) != 0;
        u32 SA = 0, S2A = 0, SB = 0, S2B = 0;
        int r0 = half * 64;
        for (int r = r0; r < r0 + 64; r += 2) {
            ulonglong2 a0 = *(const ulonglong2*)&lb[r][0];
            ulonglong2 a1 = *(const ulonglong2*)&lb[r][2];
            ulonglong2 b0 = *(const ulonglong2*)&lb[r+1][0];
            ulonglong2 b1 = *(const ulonglong2*)&lb[r+1][2];
            u32 hqa = hq_from_bits(a0.x, a0.y, a1.x, a1.y,
                                   wq0, wq1, wy0, wy1, hasY, (a1.x | a1.y) != 0);
            u32 hqb = hq_from_bits(b0.x, b0.y, b1.x, b1.y,
                                   wq0, wq1, wy0, wy1, hasY, (b1.x | b1.y) != 0);
            SA += hqa; S2A += hqa * hqa;
            SB += hqb; S2B += hqb * hqb;
        }
        int pidx = j * NPART + bid * 2 + half;
        hP[pidx] = SA + SB; h2P[pidx] = S2A + S2B;
    }
}

// R1: reduce integer h-stats -> fold BN2 into  z = fma(hq, c1q, c0)
__global__ __launch_bounds__(256) void r1_hreduce(
        const u32* __restrict__ hP, const u32* __restrict__ h2P,
        const float* __restrict__ g2, const float* __restrict__ b2,
        float* __restrict__ bn2c) {
    int j = blockIdx.x, tid = threadIdx.x;
    u32 s = 0; u64 s2 = 0;
    for (int k = tid; k < NPART; k += 256) { s += hP[j*NPART+k]; s2 += (u64)h2P[j*NPART+k]; }
    for (int off = 32; off; off >>= 1) { s += __shfl_down(s, off, 64); s2 += __shfl_down(s2, off, 64); }
    __shared__ u32 as_[4]; __shared__ u64 as2_[4];
    int lane = tid & 63, wave = tid >> 6;
    if (lane == 0) { as_[wave] = s; as2_[wave] = s2; }
    __syncthreads();
    if (tid == 0) {
        u32 S = as_[0] + as_[1] + as_[2] + as_[3];
        u64 S2 = as2_[0] + as2_[1] + as2_[2] + as2_[3];
        double m2 = (double)S * 0.25 / (double)BATCH;
        double e2 = (double)S2 * 0.0625 / (double)BATCH;
        double v2 = e2 - m2 * m2;
        float rs = (float)(1.0 / sqrt(v2 + 1e-5));
        float c1 = rs * g2[j];
        float c0 = fmaf(-(float)m2, c1, b2[j]);
        bn2c[j] = c1 * 0.25f; bn2c[128 + j] = c0;
    }
}

// K2: stage bits in LDS, recompute hq, softsign stats (dual f32 accumulators)
__global__ __launch_bounds__(256) void k2_sstats(
        const u64* __restrict__ xbits, const u64* __restrict__ wbits,
        const float* __restrict__ bn2c,
        float* __restrict__ sS, float* __restrict__ sS2) {
    __shared__ u64 lb[128][4];
    int tid = threadIdx.x;
    ((ulonglong2*)&lb[0][0])[tid] =
        ((const ulonglong2*)(xbits + (size_t)blockIdx.x * 512))[tid];
    __syncthreads();
    int j = tid & 127, half = tid >> 7;
    if (j >= DIM) return;
    u64 q0 = wbits[j*4+0], q1 = wbits[j*4+1], y0 = wbits[j*4+2], y1 = wbits[j*4+3];
    bool hasY = (y0 | y1) != 0;
    float c1q = bn2c[j], c0 = bn2c[128 + j];
    float SsA = 0.f, Ss2A = 0.f, SsB = 0.f, Ss2B = 0.f;
    int r0 = half * 64;
    for (int r = r0; r < r0 + 64; r += 2) {
        u64 z0 = lb[r][2], z1 = lb[r][3];
        u32 hqa = hq_from_bits(lb[r][0], lb[r][1], z0, z1,
                               q0, q1, y0, y1, hasY, (z0 | z1) != 0);
        u64 w0 = lb[r+1][2], w1 = lb[r+1][3];
        u32 hqb = hq_from_bits(lb[r+1][0], lb[r+1][1], w0, w1,
                               q0, q1, y0, y1, hasY, (w0 | w1) != 0);
        float za = fmaf((float)hqa, c1q, c0);
        float sa = za * __builtin_amdgcn_rcpf(1.f + fabsf(za));
        SsA += sa; Ss2A = fmaf(sa, sa, Ss2A);
        float zb = fmaf((float)hqb, c1q, c0);
        float sb = zb * __builtin_amdgcn_rcpf(1.f + fabsf(zb));
        SsB += sb; Ss2B = fmaf(sb, sb, Ss2B);
    }
    int pidx = j * NPART + blockIdx.x * 2 + half;
    sS[pidx] = SsA + SsB; sS2[pidx] = Ss2A + Ss2B;
}

// R2: reduce softsign stats (f64), fold BN1, derive the two integer
// thresholds per column; lin_w binarize computed inline.
__global__ __launch_bounds__(256) void r2_sreduce(
        const float* __restrict__ sS, const float* __restrict__ sS2,
        const float* __restrict__ g1, const float* __restrict__ b1,
        const float* __restrict__ bn2c, const float* __restrict__ lw,
        u32* __restrict__ meta) {
    int j = blockIdx.x, tid = threadIdx.x;
    double s = 0.0, s2 = 0.0;
    for (int k = tid; k < NPART; k += 256) { s += (double)sS[j*NPART+k]; s2 += (double)sS2[j*NPART+k]; }
    for (int off = 32; off; off >>= 1) { s += __shfl_down(s, off, 64); s2 += __shfl_down(s2, off, 64); }
    __shared__ double ds_[4], ds2_[4];
    __shared__ float sd1, sd0;
    __shared__ u32 cnt[3];
    __shared__ u32 sfirst, slast;
    int lane = tid & 63, wave = tid >> 6;
    if (lane == 0) { ds_[wave] = s; ds2_[wave] = s2; }
    if (tid < 3) cnt[tid] = 0;
    __syncthreads();
    if (tid == 0) {
        double S = ds_[0] + ds_[1] + ds_[2] + ds_[3];
        double S2 = ds2_[0] + ds2_[1] + ds2_[2] + ds2_[3];
        double m1 = S / (double)BATCH;
        double v1 = S2 / (double)BATCH - m1 * m1;
        float rs = (float)(1.0 / sqrt(v1 + 1e-5));
        float d1 = rs * g1[j];
        float d0 = fmaf(-(float)m1, d1, b1[j]);
        sd1 = d1; sd0 = d0;
    }
    __syncthreads();
    float c1q = bn2c[j], c0 = bn2c[128 + j];
    float d1 = sd1, d0 = sd0;
    for (int hq = tid; hq < 481; hq += 256) {
        float z = fmaf((float)hq, c1q, c0);
        float sv = z * __builtin_amdgcn_rcpf(1.f + fabsf(z));
        float h1 = fmaf(sv, d1, d0);
        u32 hb2 = h1 > 0.f ? 2u : (h1 == 0.f ? 1u : 0u);
        atomicAdd(&cnt[hb2], 1u);
        if (hq == 0)   sfirst = hb2;
        if (hq == 480) slast  = hb2;
    }
    __syncthreads();
    if (tid == 0) {
        u32 n0 = cnt[0], n1 = cnt[1], n2 = cnt[2];
        u32 dec = (slast < sfirst) ? 1u : 0u;
        u32 A = dec ? n2 : n0;
        u32 B = A + n1;
        float w0 = lw[j], w1 = lw[DIM + j];
        u32 l0 = w0 > 0.f ? 2u : (w0 == 0.f ? 1u : 0u);
        u32 l1 = w1 > 0.f ? 2u : (w1 == 0.f ? 1u : 0u);
        meta[2*j]   = A | (B << 9) | (dec << 18);
        meta[2*j+1] = l0 | (l1 << 16);
    }
}

// K3: thread <-> row, chunked-register column loop, per-block stat partials
// to distinct addresses (no global atomics).
__global__ __launch_bounds__(256) void k3_out(
        const u64* __restrict__ xbits, const u64* __restrict__ wbits,
        const u32* __restrict__ meta, const u32* __restrict__ oacc,
        u32* __restrict__ oqbuf, u32* __restrict__ oP) {
    __shared__ u64 sq0[DIM], sq1[DIM], smw[DIM], sy0[DIM], sy1[DIM];
    int tid = threadIdx.x;
    for (int k = tid; k < DIM; k += 256) {
        sq0[k] = wbits[k*4+0]; sq1[k] = wbits[k*4+1];
        sy0[k] = wbits[k*4+2]; sy1[k] = wbits[k*4+3];
        smw[k] = (u64)meta[2*k] | ((u64)meta[2*k+1] << 32);
    }
    __syncthreads();
    size_t row = (size_t)blockIdx.x * 256 + tid;
    const ulonglong2* xb = (const ulonglong2*)xbits;
    ulonglong2 rp = xb[row*2], rz = xb[row*2+1];
    u64 p0 = rp.x, p1 = rp.y, z0 = rz.x, z1 = rz.y;
    u32 oq = 0;
    for (int c = 0; c < DIM; c += CH) {
        ulonglong2 A[CH/2], B[CH/2], Mw[CH/2];
        #pragma unroll
        for (int t = 0; t < CH/2; ++t) {
            A[t] = *(const ulonglong2*)&sq0[c + 2*t];
            B[t] = *(const ulonglong2*)&sq1[c + 2*t];
            Mw[t] = *(const ulonglong2*)&smw[c + 2*t];
        }
        #pragma unroll
        for (int t = 0; t < CH/2; ++t) {
            proc_col(p0, p1, A[t].x, B[t].x, Mw[t].x, oq);
            proc_col(p0, p1, A[t].y, B[t].y, Mw[t].y, oq);
        }
    }
    bool slow = (oacc[8] != 0) | ((z0 | z1) != 0);
    if (__any(slow)) {
        if (slow) {          // exact full recompute (expected ~2 rows/batch)
            oq = 0;
            for (int j = 0; j < DIM; ++j) {
                u64 y0 = sy0[j], y1 = sy1[j];
                u32 hq = hq_from_bits(p0, p1, z0, z1, sq0[j], sq1[j], y0, y1,
                                      (y0 | y1) != 0, (z0 | z1) != 0);
                u64 mw = smw[j];
                u32 m = (u32)mw, lw = (u32)(mw >> 32);
                u32 ge = (u32)(hq >= (m & 511u)) + (u32)(hq >= ((m >> 9) & 511u));
                oq += ((m & (1u << 18)) ? 2u - ge : ge) * lw;
            }
        }
    }
    oqbuf[row] = oq;
    u32 o0 = oq & 0xffffu, o1 = oq >> 16;
    u32 a = o0, b = o1, c2 = o0 * o0, d2 = o1 * o1;
    for (int off = 32; off; off >>= 1) {
        a += __shfl_down(a, off, 64);  b += __shfl_down(b, off, 64);
        c2 += __shfl_down(c2, off, 64); d2 += __shfl_down(d2, off, 64);
    }
    __shared__ u32 r0_[4], r1_[4], r2_[4], r3_[4];
    int lane = tid & 63, wv = tid >> 6;
    if (lane == 0) { r0_[wv] = a; r1_[wv] = b; r2_[wv] = c2; r3_[wv] = d2; }
    __syncthreads();
    if (tid == 0) {
        u32* dst = oP + (size_t)blockIdx.x * 4;
        dst[0] = r0_[0] + r0_[1] + r0_[2] + r0_[3];
        dst[1] = r1_[0] + r1_[1] + r1_[2] + r1_[3];
        dst[2] = r2_[0] + r2_[1] + r2_[2] + r2_[3];
        dst[3] = r3_[0] + r3_[1] + r3_[2] + r3_[3];
    }
}

// K4: each block redundantly reduces the 16KB oP partials (exact integers,
// f64 finalize), then normalizes its 256 rows + 2-class log_softmax.
__global__ __launch_bounds__(256) void k4_final(
        const u32* __restrict__ oqbuf, const u32* __restrict__ oP,
        float* __restrict__ out) {
    int tid = threadIdx.x;
    u64 a = 0, b = 0, c2 = 0, d2 = 0;
    for (int k = tid; k < NBLK3; k += 256) {
        uint4 p = ((const uint4*)oP)[k];
        a += p.x; b += p.y; c2 += p.z; d2 += p.w;
    }
    for (int off = 32; off; off >>= 1) {
        a += __shfl_down(a, off, 64);  b += __shfl_down(b, off, 64);
        c2 += __shfl_down(c2, off, 64); d2 += __shfl_down(d2, off, 64);
    }
    __shared__ u64 s0_[4], s1_[4], s2_[4], s3_[4];
    __shared__ float sfin[4];
    int lane = tid & 63, wv = tid >> 6;
    if (lane == 0) { s0_[wv] = a; s1_[wv] = b; s2_[wv] = c2; s3_[wv] = d2; }
    __syncthreads();
    if (tid < 2) {
        u64 S  = (tid == 0) ? s0_[0]+s0_[1]+s0_[2]+s0_[3] : s1_[0]+s1_[1]+s1_[2]+s1_[3];
        u64 S2 = (tid == 0) ? s2_[0]+s2_[1]+s2_[2]+s2_[3] : s3_[0]+s3_[1]+s3_[2]+s3_[3];
        double av = (double)S * 0.25 / (double)BATCH;
        double e2 = (double)S2 * 0.0625 / (double)BATCH;
        double vo = e2 - av * av;
        sfin[tid]     = (float)av;
        sfin[2 + tid] = (float)(1.0 / sqrt(vo + 1e-5));
    }
    __syncthreads();
    size_t row = (size_t)blockIdx.x * 256 + tid;
    u32 v = oqbuf[row];
    float o0 = ((float)(v & 0xffffu) * 0.25f - sfin[0]) * sfin[2];
    float o1 = ((float)(v >> 16)     * 0.25f - sfin[1]) * sfin[3];
    float m = fmaxf(o0, o1);
    float l0 = o0 - m, l1 = o1 - m;
    float ls = logf(expf(l0) + expf(l1));
    ((float2*)out)[row] = make_float2(l0 - ls, l1 - ls);
}

extern "C" void kernel_launch(void* const* d_in, const int* in_sizes, int n_in,
                              void* d_out, int out_size, void* d_ws, size_t ws_size,
                              hipStream_t stream) {
    const float* x  = (const float*)d_in[0];
    const float* cw = (const float*)d_in[1];
    const float* g2 = (const float*)d_in[2];
    const float* b2 = (const float*)d_in[3];
    const float* g1 = (const float*)d_in[4];
    const float* b1 = (const float*)d_in[5];
    const float* lw = (const float*)d_in[6];
    // d_in[7] (lin_b) cancels through the final no-affine batchnorm
    float* out = (float*)d_out;
    if (ws_size < (size_t)WS_TOTAL) return;   // fail loudly via poisoned d_out

    char* ws = (char*)d_ws;
    u64* xbits = (u64*)(ws + WS_XBITS);
    u64* wbits = (u64*)(ws + WS_WBITS);
    u32* meta  = (u32*)(ws + WS_META);
    u32* hP    = (u32*)(ws + WS_HS);
    u32* h2P   = (u32*)(ws + WS_HS2);
    float* sP  = (float*)(ws + WS_SS);
    float* s2P = (float*)(ws + WS_SS2);
    float* bn2c = (float*)(ws + WS_BN2C);
    u32* oqbuf = (u32*)(ws + WS_OQ);
    u32* oacc  = (u32*)(ws + WS_OACC);
    u32* oP    = (u32*)(ws + WS_OP);

    kp_pack   <<<NBLKP, 256, 0, stream>>>(x, xbits);
    k1b_hstats<<<NBLK1, 256, 0, stream>>>(xbits, cw, wbits, oacc, hP, h2P);
    r1_hreduce<<<DIM, 256, 0, stream>>>(hP, h2P, g2, b2, bn2c);
    k2_sstats <<<NBLK1, 256, 0, stream>>>(xbits, wbits, bn2c, sP, s2P);
    r2_sreduce<<<DIM, 256, 0, stream>>>(sP, s2P, g1, b1, bn2c, lw, meta);
    k3_out    <<<NBLK3, 256, 0, stream>>>(xbits, wbits, meta, oacc, oqbuf, oP);
    k4_final  <<<NBLK3, 256, 0, stream>>>(oqbuf, oP, out);
}

// Round 14
// 116.471 us; speedup vs baseline: 1.3241x; 1.0296x over previous
//
#include <hip/hip_runtime.h>
#include <stdint.h>
#include <math.h>

typedef unsigned long long u64;
typedef uint32_t u32;

#define BATCH   262144
#define DIM     120
#define NBLKP   2048      // kp: 128 rows per block
#define NBLK1   2048      // k1b/k2: 128 rows per block
#define NPART   4096      // partial slots per column (2 halves * 2048 blocks)
#define CH      8         // k3: columns per register chunk
#define NBLK3   1024      // k3 blocks (256 rows each)

// Bit layout (x and w MUST match): element c -> word (c>>6), bit (c&63).
// word0 = cols 0..63, word1 = cols 64..119 (56 bits used).

// ---------------- workspace layout (bytes) ----------------
#define WS_XBITS   0              // u64[BATCH*4]            8,388,608
#define WS_WBITS   8388608        // u64[128*4]
#define WS_META    8393216        // u32[256]
#define WS_HS      8394240        // u32[120*4096]
#define WS_HS2     10360320      // u32[120*4096]
#define WS_SS      12326400      // f32[120*4096]
#define WS_SS2     14292480      // f32[120*4096]
#define WS_BN2C    16258560      // f32[256]
#define WS_OQ      16259584      // u32[BATCH]
#define WS_OACC    17308160      // u32 yflag @ word 8
#define WS_OP      17308224      // u32[1024*4]
#define WS_TOTAL   17324624

__device__ __forceinline__ u32 hq_from_bits(u64 p0, u64 p1, u64 z0, u64 z1,
                                            u64 q0, u64 q1, u64 y0, u64 y1,
                                            bool hasY, bool hasZ) {
    u32 hq = (u32)(__popcll(p0 & q0) + __popcll(p1 & q1)) << 2;
    if (hasY)
        hq += 2u * (u32)(__popcll(p0 & y0) + __popcll(p1 & y1))
            + (u32)(__popcll(z0 & y0) + __popcll(z1 & y1));
    if (hasZ)
        hq += 2u * (u32)(__popcll(z0 & q0) + __popcll(z1 & q1));
    return hq;   // == 4 * h, exact integer in [0, 480]
}

__device__ __forceinline__ void proc_col(u64 p0, u64 p1, u64 q0, u64 q1,
                                         u64 mw, u32& oq) {
    u32 hq = ((u32)(__popcll(p0 & q0) + __popcll(p1 & q1))) << 2;
    u32 m  = (u32)mw;
    u32 lw = (u32)(mw >> 32);
    u32 ge = (u32)(hq >= (m & 511u)) + (u32)(hq >= ((m >> 9) & 511u));
    u32 hb2 = (m & (1u << 18)) ? 2u - ge : ge;
    oq += hb2 * lw;
}

__device__ __forceinline__ u32 even_bits(u32 v) {
    u32 e = v & 0x55555555u;
    e = (e | (e >> 1)) & 0x33333333u;
    e = (e | (e >> 2)) & 0x0F0F0F0Fu;
    e = (e | (e >> 4)) & 0x00FF00FFu;
    e = (e | (e >> 8)) & 0x0000FFFFu;
    return e;
}

// KP: ballot-free, branch-free pack.
// Phase A: pure streaming loop — 15 unconditional coalesced independent
// float4 loads per thread (no convergent ops -> compiler pipelines deep),
// 2-bit codes per element packed into 1 byte -> LDS.
// Phase B: thread r assembles row r from 30 LDS bytes (funnel-merge),
// even/odd-bit extract -> p0,p1,z0,z1 (identity layout), coalesced store.
__global__ __launch_bounds__(256) void kp_pack(
        const float* __restrict__ x, u64* __restrict__ xbits) {
    __shared__ u32 codes[968];    // 3840 bytes used (128 rows * 30)
    int tid = threadIdx.x;
    size_t base = (size_t)blockIdx.x * 128;
    const float4* x4 = (const float4*)(x + base * (size_t)DIM);
    unsigned char* cb = (unsigned char*)codes;
    #pragma unroll
    for (int i = 0; i < 15; ++i) {
        int f = i * 256 + tid;
        float4 v = x4[f];
        u32 c = (v.x > 0.f ? 1u : 0u)  | (v.x == 0.f ? 2u : 0u)
              | (v.y > 0.f ? 4u : 0u)  | (v.y == 0.f ? 8u : 0u)
              | (v.z > 0.f ? 16u : 0u) | (v.z == 0.f ? 32u : 0u)
              | (v.w > 0.f ? 64u : 0u) | (v.w == 0.f ? 128u : 0u);
        cb[f] = (unsigned char)c;
    }
    __syncthreads();
    if (tid < 128) {
        int bo = tid * 30;
        int b0 = bo >> 2;
        int sh = (bo & 3) * 8;     // 0 or 16
        u32 W[9];
        #pragma unroll
        for (int i = 0; i < 9; ++i) W[i] = codes[b0 + i];
        u32 e[8], o[8];
        #pragma unroll
        for (int i = 0; i < 8; ++i) {
            u32 A = (u32)(((((u64)W[i+1]) << 32) | (u64)W[i]) >> sh);
            if (i == 7) A &= 0xFFFFu;
            e[i] = even_bits(A);
            o[i] = even_bits(A >> 1);
        }
        u64 p0 = (u64)(e[0] | (e[1] << 16)) | ((u64)(e[2] | (e[3] << 16)) << 32);
        u64 p1 = (u64)(e[4] | (e[5] << 16)) | ((u64)(e[6] | (e[7] << 16)) << 32);
        u64 z0 = (u64)(o[0] | (o[1] << 16)) | ((u64)(o[2] | (o[3] << 16)) << 32);
        u64 z1 = (u64)(o[4] | (o[5] << 16)) | ((u64)(o[6] | (o[7] << 16)) << 32);
        ulonglong2* dst = (ulonglong2*)(xbits + (base + (size_t)tid) * 4);
        dst[0] = make_ulonglong2(p0, p1);
        dst[1] = make_ulonglong2(z0, z1);
    }
}

// K1b: integer h-stats. Stages 128 rows of xbits in LDS; conv_w packed
// per-thread with 30 independent unrolled float4 loads in the identity
// layout (element c -> word c>>6, bit c&63). Block 0 publishes wbits+yflag.
__global__ __launch_bounds__(256) void k1b_hstats(
        const u64* __restrict__ xbits, const float* __restrict__ w,
        u64* __restrict__ wbits, u32* __restrict__ oacc,
        u32* __restrict__ hP, u32* __restrict__ h2P) {
    __shared__ __align__(16) u64 lb[128][4];
    __shared__ __align__(16) u64 sw[128][4];
    __shared__ u32 swf[4];
    int tid = threadIdx.x, bid = blockIdx.x;

    ((ulonglong2*)&lb[0][0])[tid] =
        ((const ulonglong2*)(xbits + (size_t)bid * 512))[tid];

    u64 q0 = 0, q1 = 0, yy0 = 0, yy1 = 0;
    if (tid < DIM) {
        const float4* row4 = (const float4*)(w + (size_t)tid * DIM);
        #pragma unroll
        for (int i = 0; i < 30; ++i) {
            float4 v = row4[i];
            u32 bp = (u32)(v.x > 0.f) | ((u32)(v.y > 0.f) << 1)
                   | ((u32)(v.z > 0.f) << 2) | ((u32)(v.w > 0.f) << 3);
            u32 bz = (u32)(v.x == 0.f) | ((u32)(v.y == 0.f) << 1)
                   | ((u32)(v.z == 0.f) << 2) | ((u32)(v.w == 0.f) << 3);
            if (i < 16) { q0 |= (u64)bp << (4 * i);        yy0 |= (u64)bz << (4 * i); }
            else        { q1 |= (u64)bp << (4 * (i - 16)); yy1 |= (u64)bz << (4 * (i - 16)); }
        }
    }
    if (tid < 128) {
        sw[tid][0] = q0; sw[tid][1] = q1; sw[tid][2] = yy0; sw[tid][3] = yy1;
    }
    {
        u64 bal = __ballot((yy0 | yy1) != 0);
        if ((tid & 63) == 0) swf[tid >> 6] = (bal != 0) ? 1u : 0u;
    }
    __syncthreads();

    if (bid == 0) {
        ((u64*)wbits)[tid]       = ((const u64*)sw)[tid];
        ((u64*)wbits)[tid + 256] = ((const u64*)sw)[tid + 256];
        if (tid == 0) oacc[8] = (swf[0] | swf[1] | swf[2] | swf[3]) ? 1u : 0u;
    }

    int j = tid & 127, half = tid >> 7;
    if (j < DIM) {
        u64 wq0 = sw[j][0], wq1 = sw[j][1], wy0 = sw[j][2], wy1 = sw[j][3];
        bool hasY = (wy0 | wy1) != 0;
        u32 SA = 0, S2A = 0, SB = 0, S2B = 0;
        int r0 = half * 64;
        for (int r = r0; r < r0 + 64; r += 2) {
            ulonglong2 a0 = *(const ulonglong2*)&lb[r][0];
            ulonglong2 a1 = *(const ulonglong2*)&lb[r][2];
            ulonglong2 b0 = *(const ulonglong2*)&lb[r+1][0];
            ulonglong2 b1 = *(const ulonglong2*)&lb[r+1][2];
            u32 hqa = hq_from_bits(a0.x, a0.y, a1.x, a1.y,
                                   wq0, wq1, wy0, wy1, hasY, (a1.x | a1.y) != 0);
            u32 hqb = hq_from_bits(b0.x, b0.y, b1.x, b1.y,
                                   wq0, wq1, wy0, wy1, hasY, (b1.x | b1.y) != 0);
            SA += hqa; S2A += hqa * hqa;
            SB += hqb; S2B += hqb * hqb;
        }
        int pidx = j * NPART + bid * 2 + half;
        hP[pidx] = SA + SB; h2P[pidx] = S2A + S2B;
    }
}

// R1: reduce integer h-stats -> fold BN2 into  z = fma(hq, c1q, c0)
__global__ __launch_bounds__(256) void r1_hreduce(
        const u32* __restrict__ hP, const u32* __restrict__ h2P,
        const float* __restrict__ g2, const float* __restrict__ b2,
        float* __restrict__ bn2c) {
    int j = blockIdx.x, tid = threadIdx.x;
    u32 s = 0; u64 s2 = 0;
    for (int k = tid; k < NPART; k += 256) { s += hP[j*NPART+k]; s2 += (u64)h2P[j*NPART+k]; }
    for (int off = 32; off; off >>= 1) { s += __shfl_down(s, off, 64); s2 += __shfl_down(s2, off, 64); }
    __shared__ u32 as_[4]; __shared__ u64 as2_[4];
    int lane = tid & 63, wave = tid >> 6;
    if (lane == 0) { as_[wave] = s; as2_[wave] = s2; }
    __syncthreads();
    if (tid == 0) {
        u32 S = as_[0] + as_[1] + as_[2] + as_[3];
        u64 S2 = as2_[0] + as2_[1] + as2_[2] + as2_[3];
        double m2 = (double)S * 0.25 / (double)BATCH;
        double e2 = (double)S2 * 0.0625 / (double)BATCH;
        double v2 = e2 - m2 * m2;
        float rs = (float)(1.0 / sqrt(v2 + 1e-5));
        float c1 = rs * g2[j];
        float c0 = fmaf(-(float)m2, c1, b2[j]);
        bn2c[j] = c1 * 0.25f; bn2c[128 + j] = c0;
    }
}

// K2: stage bits in LDS, recompute hq, softsign stats (dual f32 accumulators)
__global__ __launch_bounds__(256) void k2_sstats(
        const u64* __restrict__ xbits, const u64* __restrict__ wbits,
        const float* __restrict__ bn2c,
        float* __restrict__ sS, float* __restrict__ sS2) {
    __shared__ u64 lb[128][4];
    int tid = threadIdx.x;
    ((ulonglong2*)&lb[0][0])[tid] =
        ((const ulonglong2*)(xbits + (size_t)blockIdx.x * 512))[tid];
    __syncthreads();
    int j = tid & 127, half = tid >> 7;
    if (j >= DIM) return;
    u64 q0 = wbits[j*4+0], q1 = wbits[j*4+1], y0 = wbits[j*4+2], y1 = wbits[j*4+3];
    bool hasY = (y0 | y1) != 0;
    float c1q = bn2c[j], c0 = bn2c[128 + j];
    float SsA = 0.f, Ss2A = 0.f, SsB = 0.f, Ss2B = 0.f;
    int r0 = half * 64;
    for (int r = r0; r < r0 + 64; r += 2) {
        u64 z0 = lb[r][2], z1 = lb[r][3];
        u32 hqa = hq_from_bits(lb[r][0], lb[r][1], z0, z1,
                               q0, q1, y0, y1, hasY, (z0 | z1) != 0);
        u64 w0 = lb[r+1][2], w1 = lb[r+1][3];
        u32 hqb = hq_from_bits(lb[r+1][0], lb[r+1][1], w0, w1,
                               q0, q1, y0, y1, hasY, (w0 | w1) != 0);
        float za = fmaf((float)hqa, c1q, c0);
        float sa = za * __builtin_amdgcn_rcpf(1.f + fabsf(za));
        SsA += sa; Ss2A = fmaf(sa, sa, Ss2A);
        float zb = fmaf((float)hqb, c1q, c0);
        float sb = zb * __builtin_amdgcn_rcpf(1.f + fabsf(zb));
        SsB += sb; Ss2B = fmaf(sb, sb, Ss2B);
    }
    int pidx = j * NPART + blockIdx.x * 2 + half;
    sS[pidx] = SsA + SsB; sS2[pidx] = Ss2A + Ss2B;
}

// R2: reduce softsign stats (f64), fold BN1, derive the two integer
// thresholds per column; lin_w binarize computed inline.
__global__ __launch_bounds__(256) void r2_sreduce(
        const float* __restrict__ sS, const float* __restrict__ sS2,
        const float* __restrict__ g1, const float* __restrict__ b1,
        const float* __restrict__ bn2c, const float* __restrict__ lw,
        u32* __restrict__ meta) {
    int j = blockIdx.x, tid = threadIdx.x;
    double s = 0.0, s2 = 0.0;
    for (int k = tid; k < NPART; k += 256) { s += (double)sS[j*NPART+k]; s2 += (double)sS2[j*NPART+k]; }
    for (int off = 32; off; off >>= 1) { s += __shfl_down(s, off, 64); s2 += __shfl_down(s2, off, 64); }
    __shared__ double ds_[4], ds2_[4];
    __shared__ float sd1, sd0;
    __shared__ u32 cnt[3];
    __shared__ u32 sfirst, slast;
    int lane = tid & 63, wave = tid >> 6;
    if (lane == 0) { ds_[wave] = s; ds2_[wave] = s2; }
    if (tid < 3) cnt[tid] = 0;
    __syncthreads();
    if (tid == 0) {
        double S = ds_[0] + ds_[1] + ds_[2] + ds_[3];
        double S2 = ds2_[0] + ds2_[1] + ds2_[2] + ds2_[3];
        double m1 = S / (double)BATCH;
        double v1 = S2 / (double)BATCH - m1 * m1;
        float rs = (float)(1.0 / sqrt(v1 + 1e-5));
        float d1 = rs * g1[j];
        float d0 = fmaf(-(float)m1, d1, b1[j]);
        sd1 = d1; sd0 = d0;
    }
    __syncthreads();
    float c1q = bn2c[j], c0 = bn2c[128 + j];
    float d1 = sd1, d0 = sd0;
    for (int hq = tid; hq < 481; hq += 256) {
        float z = fmaf((float)hq, c1q, c0);
        float sv = z * __builtin_amdgcn_rcpf(1.f + fabsf(z));
        float h1 = fmaf(sv, d1, d0);
        u32 hb2 = h1 > 0.f ? 2u : (h1 == 0.f ? 1u : 0u);
        atomicAdd(&cnt[hb2], 1u);
        if (hq == 0)   sfirst = hb2;
        if (hq == 480) slast  = hb2;
    }
    __syncthreads();
    if (tid == 0) {
        u32 n0 = cnt[0], n1 = cnt[1], n2 = cnt[2];
        u32 dec = (slast < sfirst) ? 1u : 0u;
        u32 A = dec ? n2 : n0;
        u32 B = A + n1;
        float w0 = lw[j], w1 = lw[DIM + j];
        u32 l0 = w0 > 0.f ? 2u : (w0 == 0.f ? 1u : 0u);
        u32 l1 = w1 > 0.f ? 2u : (w1 == 0.f ? 1u : 0u);
        meta[2*j]   = A | (B << 9) | (dec << 18);
        meta[2*j+1] = l0 | (l1 << 16);
    }
}

// K3: thread <-> row, chunked-register column loop, per-block stat partials
// to distinct addresses (no global atomics).
__global__ __launch_bounds__(256) void k3_out(
        const u64* __restrict__ xbits, const u64* __restrict__ wbits,
        const u32* __restrict__ meta, const u32* __restrict__ oacc,
        u32* __restrict__ oqbuf, u32* __restrict__ oP) {
    __shared__ u64 sq0[DIM], sq1[DIM], smw[DIM], sy0[DIM], sy1[DIM];
    int tid = threadIdx.x;
    for (int k = tid; k < DIM; k += 256) {
        sq0[k] = wbits[k*4+0]; sq1[k] = wbits[k*4+1];
        sy0[k] = wbits[k*4+2]; sy1[k] = wbits[k*4+3];
        smw[k] = (u64)meta[2*k] | ((u64)meta[2*k+1] << 32);
    }
    __syncthreads();
    size_t row = (size_t)blockIdx.x * 256 + tid;
    const ulonglong2* xb = (const ulonglong2*)xbits;
    ulonglong2 rp = xb[row*2], rz = xb[row*2+1];
    u64 p0 = rp.x, p1 = rp.y, z0 = rz.x, z1 = rz.y;
    u32 oq = 0;
    for (int c = 0; c < DIM; c += CH) {
        ulonglong2 A[CH/2], B[CH/2], Mw[CH/2];
        #pragma unroll
        for (int t = 0; t < CH/2; ++t) {
            A[t] = *(const ulonglong2*)&sq0[c + 2*t];
            B[t] = *(const ulonglong2*)&sq1[c + 2*t];
            Mw[t] = *(const ulonglong2*)&smw[c + 2*t];
        }
        #pragma unroll
        for (int t = 0; t < CH/2; ++t) {
            proc_col(p0, p1, A[t].x, B[t].x, Mw[t].x, oq);
            proc_col(p0, p1, A[t].y, B[t].y, Mw[t].y, oq);
        }
    }
    bool slow = (oacc[8] != 0) | ((z0 | z1) != 0);
    if (__any(slow)) {
        if (slow) {          // exact full recompute (expected ~2 rows/batch)
            oq = 0;
            for (int j = 0; j < DIM; ++j) {
                u64 y0 = sy0[j], y1 = sy1[j];
                u32 hq = hq_from_bits(p0, p1, z0, z1, sq0[j], sq1[j], y0, y1,
                                      (y0 | y1) != 0, (z0 | z1) != 0);
                u64 mw = smw[j];
                u32 m = (u32)mw, lw = (u32)(mw >> 32);
                u32 ge = (u32)(hq >= (m & 511u)) + (u32)(hq >= ((m >> 9) & 511u));
                oq += ((m & (1u << 18)) ? 2u - ge : ge) * lw;
            }
        }
    }
    oqbuf[row] = oq;
    u32 o0 = oq & 0xffffu, o1 = oq >> 16;
    u32 a = o0, b = o1, c2 = o0 * o0, d2 = o1 * o1;
    for (int off = 32; off; off >>= 1) {
        a += __shfl_down(a, off, 64);  b += __shfl_down(b, off, 64);
        c2 += __shfl_down(c2, off, 64); d2 += __shfl_down(d2, off, 64);
    }
    __shared__ u32 r0_[4], r1_[4], r2_[4], r3_[4];
    int lane = tid & 63, wv = tid >> 6;
    if (lane == 0) { r0_[wv] = a; r1_[wv] = b; r2_[wv] = c2; r3_[wv] = d2; }
    __syncthreads();
    if (tid == 0) {
        u32* dst = oP + (size_t)blockIdx.x * 4;
        dst[0] = r0_[0] + r0_[1] + r0_[2] + r0_[3];
        dst[1] = r1_[0] + r1_[1] + r1_[2] + r1_[3];
        dst[2] = r2_[0] + r2_[1] + r2_[2] + r2_[3];
        dst[3] = r3_[0] + r3_[1] + r3_[2] + r3_[3];
    }
}

// K4: each block redundantly reduces the 16KB oP partials (exact integers,
// f64 finalize), then normalizes its 256 rows + 2-class log_softmax.
__global__ __launch_bounds__(256) void k4_final(
        const u32* __restrict__ oqbuf, const u32* __restrict__ oP,
        float* __restrict__ out) {
    int tid = threadIdx.x;
    u64 a = 0, b = 0, c2 = 0, d2 = 0;
    for (int k = tid; k < NBLK3; k += 256) {
        uint4 p = ((const uint4*)oP)[k];
        a += p.x; b += p.y; c2 += p.z; d2 += p.w;
    }
    for (int off = 32; off; off >>= 1) {
        a += __shfl_down(a, off, 64);  b += __shfl_down(b, off, 64);
        c2 += __shfl_down(c2, off, 64); d2 += __shfl_down(d2, off, 64);
    }
    __shared__ u64 s0_[4], s1_[4], s2_[4], s3_[4];
    __shared__ float sfin[4];
    int lane = tid & 63, wv = tid >> 6;
    if (lane == 0) { s0_[wv] = a; s1_[wv] = b; s2_[wv] = c2; s3_[wv] = d2; }
    __syncthreads();
    if (tid < 2) {
        u64 S  = (tid == 0) ? s0_[0]+s0_[1]+s0_[2]+s0_[3] : s1_[0]+s1_[1]+s1_[2]+s1_[3];
        u64 S2 = (tid == 0) ? s2_[0]+s2_[1]+s2_[2]+s2_[3] : s3_[0]+s3_[1]+s3_[2]+s3_[3];
        double av = (double)S * 0.25 / (double)BATCH;
        double e2 = (double)S2 * 0.0625 / (double)BATCH;
        double vo = e2 - av * av;
        sfin[tid]     = (float)av;
        sfin[2 + tid] = (float)(1.0 / sqrt(vo + 1e-5));
    }
    __syncthreads();
    size_t row = (size_t)blockIdx.x * 256 + tid;
    u32 v = oqbuf[row];
    float o0 = ((float)(v & 0xffffu) * 0.25f - sfin[0]) * sfin[2];
    float o1 = ((float)(v >> 16)     * 0.25f - sfin[1]) * sfin[3];
    float m = fmaxf(o0, o1);
    float l0 = o0 - m, l1 = o1 - m;
    float ls = logf(expf(l0) + expf(l1));
    ((float2*)out)[row] = make_float2(l0 - ls, l1 - ls);
}

extern "C" void kernel_launch(void* const* d_in, const int* in_sizes, int n_in,
                              void* d_out, int out_size, void* d_ws, size_t ws_size,
                              hipStream_t stream) {
    const float* x  = (const float*)d_in[0];
    const float* cw = (const float*)d_in[1];
    const float* g2 = (const float*)d_in[2];
    const float* b2 = (const float*)d_in[3];
    const float* g1 = (const float*)d_in[4];
    const float* b1 = (const float*)d_in[5];
    const float* lw = (const float*)d_in[6];
    // d_in[7] (lin_b) cancels through the final no-affine batchnorm
    float* out = (float*)d_out;
    if (ws_size < (size_t)WS_TOTAL) return;   // fail loudly via poisoned d_out

    char* ws = (char*)d_ws;
    u64* xbits = (u64*)(ws + WS_XBITS);
    u64* wbits = (u64*)(ws + WS_WBITS);
    u32* meta  = (u32*)(ws + WS_META);
    u32* hP    = (u32*)(ws + WS_HS);
    u32* h2P   = (u32*)(ws + WS_HS2);
    float* sP  = (float*)(ws + WS_SS);
    float* s2P = (float*)(ws + WS_SS2);
    float* bn2c = (float*)(ws + WS_BN2C);
    u32* oqbuf = (u32*)(ws + WS_OQ);
    u32* oacc  = (u32*)(ws + WS_OACC);
    u32* oP    = (u32*)(ws + WS_OP);

    kp_pack   <<<NBLKP, 256, 0, stream>>>(x, xbits);
    k1b_hstats<<<NBLK1, 256, 0, stream>>>(xbits, cw, wbits, oacc, hP, h2P);
    r1_hreduce<<<DIM, 256, 0, stream>>>(hP, h2P, g2, b2, bn2c);
    k2_sstats <<<NBLK1, 256, 0, stream>>>(xbits, wbits, bn2c, sP, s2P);
    r2_sreduce<<<DIM, 256, 0, stream>>>(sP, s2P, g1, b1, bn2c, lw, meta);
    k3_out    <<<NBLK3, 256, 0, stream>>>(xbits, wbits, meta, oacc, oqbuf, oP);
    k4_final  <<<NBLK3, 256, 0, stream>>>(oqbuf, oP, out);
}

// Round 15
// 111.377 us; speedup vs baseline: 1.3846x; 1.0457x over previous
//
#include <hip/hip_runtime.h>
#include <stdint.h>
#include <math.h>

typedef unsigned long long u64;
typedef uint32_t u32;

#define BATCH   262144
#define DIM     120
#define NBLK1   2048      // k1/k2: 128 rows per block
#define NPART   4096      // partial slots per column (2 halves * 2048 blocks)
#define CH      8         // k3: columns per register chunk
#define NBLK3   1024      // k3 blocks (256 rows each)

// Bit permutation (x and w MUST match): element c -> plane (c&3), bit (c>>2).
// p0 = plane0 | plane1<<30 ; p1 = plane2 | plane3<<30 (60 bits used).

// ---------------- workspace layout (bytes) ----------------
#define WS_XBITS   0              // u64[BATCH*4]            8,388,608
#define WS_WBITS   8388608        // u64[128*4]
#define WS_META    8393216        // u32[256]
#define WS_HS      8394240        // u32[120*4096]
#define WS_HS2     10360320      // u32[120*4096]
#define WS_SS      12326400      // f32[120*4096]
#define WS_SS2     14292480      // f32[120*4096]
#define WS_BN2C    16258560      // f32[256]
#define WS_OQ      16259584      // u32[BATCH]
#define WS_OACC    17308160      // u32 yflag @ word 8
#define WS_OP      17308224      // u32[1024*4]
#define WS_TOTAL   17324624

__device__ __forceinline__ u32 hq_from_bits(u64 p0, u64 p1, u64 z0, u64 z1,
                                            u64 q0, u64 q1, u64 y0, u64 y1,
                                            bool hasY, bool hasZ) {
    u32 hq = (u32)(__popcll(p0 & q0) + __popcll(p1 & q1)) << 2;
    if (hasY)
        hq += 2u * (u32)(__popcll(p0 & y0) + __popcll(p1 & y1))
            + (u32)(__popcll(z0 & y0) + __popcll(z1 & y1));
    if (hasZ)
        hq += 2u * (u32)(__popcll(z0 & q0) + __popcll(z1 & q1));
    return hq;   // == 4 * h, exact integer in [0, 480]
}

__device__ __forceinline__ void proc_col(u64 p0, u64 p1, u64 q0, u64 q1,
                                         u64 mw, u32& oq) {
    u32 hq = ((u32)(__popcll(p0 & q0) + __popcll(p1 & q1))) << 2;
    u32 m  = (u32)mw;
    u32 lw = (u32)(mw >> 32);
    u32 ge = (u32)(hq >= (m & 511u)) + (u32)(hq >= ((m >> 9) & 511u));
    u32 hb2 = (m & (1u << 18)) ? 2u - ge : ge;
    oq += hb2 * lw;
}

// K1 (kw_pack fused): 2048 blocks x 128 rows. The x-pack is software-
// pipelined 8-DEEP: a rolling buf[8] of float4 loads whose issue points are
// pinned ABOVE the convergent ballots by asm memory fences (loads cannot
// sink across them; no waitcnt is forced). Lanes l>=30 read a dummy
// address (x base) — their ballot bits are discarded by the 30-bit mask.
__global__ __launch_bounds__(256) void k1_pack_hstats(
        const float* __restrict__ x, const float* __restrict__ w,
        u64* __restrict__ wbits, u32* __restrict__ oacc,
        u64* __restrict__ xbits, u32* __restrict__ hP, u32* __restrict__ h2P) {
    __shared__ __align__(16) u64 lb[128][4];
    __shared__ __align__(16) u64 sw[128][4];
    __shared__ u32 swf[4];
    int tid = threadIdx.x, lane = tid & 63, wv = tid >> 6;
    int l = lane & 31, h = lane >> 5;
    int bid = blockIdx.x;
    const u64 M = 0x3FFFFFFFull;

#define PACKROW(dst, v, r) do { \
    u64 m0 = __ballot((v).x > 0.f), m1 = __ballot((v).y > 0.f); \
    u64 m2 = __ballot((v).z > 0.f), m3 = __ballot((v).w > 0.f); \
    u64 n0 = __ballot((v).x == 0.f), n1 = __ballot((v).y == 0.f); \
    u64 n2 = __ballot((v).z == 0.f), n3 = __ballot((v).w == 0.f); \
    if (l == 0) { u32 sh = h ? 32 : 0; \
        dst[r][0] = ((m0>>sh)&M) | (((m1>>sh)&M) << 30); \
        dst[r][1] = ((m2>>sh)&M) | (((m3>>sh)&M) << 30); \
        dst[r][2] = ((n0>>sh)&M) | (((n1>>sh)&M) << 30); \
        dst[r][3] = ((n2>>sh)&M) | (((n3>>sh)&M) << 30); } \
} while (0)

    // ---- x-pack addressing: row for iteration it = it*8 + (wv*2 + h) ----
    int rb = wv * 2 + h;               // 0..7
    const float* lp;
    size_t step;                        // floats per iteration
    if (l < 30) { lp = x + ((size_t)bid * 128 + rb) * DIM + l * 4; step = 8 * DIM; }
    else        { lp = x; step = 0; }  // dummy reads; ballot bits masked out

    // ---- prologue: issue 8 x-loads, fence them above everything below ----
    float4 buf[8];
    #pragma unroll
    for (int k = 0; k < 8; ++k)
        buf[k] = *(const float4*)(lp + (size_t)k * step);
    asm volatile("" ::: "memory");

    // ---- conv_w pack (whole 120x120 per block; L2-resident) — the x
    // prologue loads fly during these ballots ----
    u64 accy = 0;
    for (int jj = wv * 2; jj < DIM; jj += 8) {
        int j = jj + h;
        float4 v = make_float4(-1.f, -1.f, -1.f, -1.f);
        if (l < 30) v = *(const float4*)(w + (size_t)j * DIM + l * 4);
        u64 n0 = __ballot(v.x == 0.f), n1 = __ballot(v.y == 0.f);
        u64 n2 = __ballot(v.z == 0.f), n3 = __ballot(v.w == 0.f);
        accy |= (n0 | n1 | n2 | n3);
        u64 m0 = __ballot(v.x > 0.f), m1 = __ballot(v.y > 0.f);
        u64 m2 = __ballot(v.z > 0.f), m3 = __ballot(v.w > 0.f);
        if (l == 0) {
            u32 sh = h ? 32 : 0;
            sw[j][0] = ((m0>>sh)&M) | (((m1>>sh)&M) << 30);
            sw[j][1] = ((m2>>sh)&M) | (((m3>>sh)&M) << 30);
            sw[j][2] = ((n0>>sh)&M) | (((n1>>sh)&M) << 30);
            sw[j][3] = ((n2>>sh)&M) | (((n3>>sh)&M) << 30);
        }
    }
    if (tid >= 120 && tid < 128) { sw[tid][0]=0; sw[tid][1]=0; sw[tid][2]=0; sw[tid][3]=0; }
    { u32 af = __any(accy != 0) ? 1u : 0u; if (lane == 0) swf[wv] = af; }

    // ---- x pack main loop: 16 iterations, 8 loads always in flight ----
    #pragma unroll
    for (int it = 0; it < 16; ++it) {
        const int k = it & 7;
        float4 cur = buf[k];           // waits only for the oldest load
        if (it + 8 < 16)
            buf[k] = *(const float4*)(lp + (size_t)(it + 8) * step);
        asm volatile("" ::: "memory"); // refill cannot sink below ballots
        PACKROW(lb, cur, it * 8 + rb);
    }
    __syncthreads();

    // ---- publish wbits/yflag (block 0) + store xbits ----
    if (bid == 0) {
        ((u64*)wbits)[tid]       = ((const u64*)sw)[tid];
        ((u64*)wbits)[tid + 256] = ((const u64*)sw)[tid + 256];
        if (tid == 0) oacc[8] = (swf[0] | swf[1] | swf[2] | swf[3]) ? 1u : 0u;
    }
    ((ulonglong2*)(xbits + (size_t)bid * 512))[tid] =
        ((const ulonglong2*)&lb[0][0])[tid];

    // ---- integer h-stats: thread <-> column, 2-row ILP accumulators ----
    int j = tid & 127, half = tid >> 7;
    if (j < DIM) {
        u64 q0 = sw[j][0], q1 = sw[j][1], y0 = sw[j][2], y1 = sw[j][3];
        bool hasY = (y0 | y1) != 0;
        u32 SA = 0, S2A = 0, SB = 0, S2B = 0;
        int r0 = half * 64;
        for (int r = r0; r < r0 + 64; r += 2) {
            ulonglong2 a0 = *(const ulonglong2*)&lb[r][0];
            ulonglong2 a1 = *(const ulonglong2*)&lb[r][2];
            ulonglong2 b0 = *(const ulonglong2*)&lb[r+1][0];
            ulonglong2 b1 = *(const ulonglong2*)&lb[r+1][2];
            u32 hqa = hq_from_bits(a0.x, a0.y, a1.x, a1.y,
                                   q0, q1, y0, y1, hasY, (a1.x | a1.y) != 0);
            u32 hqb = hq_from_bits(b0.x, b0.y, b1.x, b1.y,
                                   q0, q1, y0, y1, hasY, (b1.x | b1.y) != 0);
            SA += hqa; S2A += hqa * hqa;
            SB += hqb; S2B += hqb * hqb;
        }
        int pidx = j * NPART + bid * 2 + half;
        hP[pidx] = SA + SB; h2P[pidx] = S2A + S2B;
    }
#undef PACKROW
}

// R1: reduce integer h-stats -> fold BN2 into  z = fma(hq, c1q, c0)
__global__ __launch_bounds__(256) void r1_hreduce(
        const u32* __restrict__ hP, const u32* __restrict__ h2P,
        const float* __restrict__ g2, const float* __restrict__ b2,
        float* __restrict__ bn2c) {
    int j = blockIdx.x, tid = threadIdx.x;
    u32 s = 0; u64 s2 = 0;
    for (int k = tid; k < NPART; k += 256) { s += hP[j*NPART+k]; s2 += (u64)h2P[j*NPART+k]; }
    for (int off = 32; off; off >>= 1) { s += __shfl_down(s, off, 64); s2 += __shfl_down(s2, off, 64); }
    __shared__ u32 as_[4]; __shared__ u64 as2_[4];
    int lane = tid & 63, wave = tid >> 6;
    if (lane == 0) { as_[wave] = s; as2_[wave] = s2; }
    __syncthreads();
    if (tid == 0) {
        u32 S = as_[0] + as_[1] + as_[2] + as_[3];
        u64 S2 = as2_[0] + as2_[1] + as2_[2] + as2_[3];
        double m2 = (double)S * 0.25 / (double)BATCH;
        double e2 = (double)S2 * 0.0625 / (double)BATCH;
        double v2 = e2 - m2 * m2;
        float rs = (float)(1.0 / sqrt(v2 + 1e-5));
        float c1 = rs * g2[j];
        float c0 = fmaf(-(float)m2, c1, b2[j]);
        bn2c[j] = c1 * 0.25f; bn2c[128 + j] = c0;
    }
}

// K2: stage bits in LDS, recompute hq, softsign stats (dual f32 accumulators)
__global__ __launch_bounds__(256) void k2_sstats(
        const u64* __restrict__ xbits, const u64* __restrict__ wbits,
        const float* __restrict__ bn2c,
        float* __restrict__ sS, float* __restrict__ sS2) {
    __shared__ u64 lb[128][4];
    int tid = threadIdx.x;
    ((ulonglong2*)&lb[0][0])[tid] =
        ((const ulonglong2*)(xbits + (size_t)blockIdx.x * 512))[tid];
    __syncthreads();
    int j = tid & 127, half = tid >> 7;
    if (j >= DIM) return;
    u64 q0 = wbits[j*4+0], q1 = wbits[j*4+1], y0 = wbits[j*4+2], y1 = wbits[j*4+3];
    bool hasY = (y0 | y1) != 0;
    float c1q = bn2c[j], c0 = bn2c[128 + j];
    float SsA = 0.f, Ss2A = 0.f, SsB = 0.f, Ss2B = 0.f;
    int r0 = half * 64;
    for (int r = r0; r < r0 + 64; r += 2) {
        u64 z0 = lb[r][2], z1 = lb[r][3];
        u32 hqa = hq_from_bits(lb[r][0], lb[r][1], z0, z1,
                               q0, q1, y0, y1, hasY, (z0 | z1) != 0);
        u64 w0 = lb[r+1][2], w1 = lb[r+1][3];
        u32 hqb = hq_from_bits(lb[r+1][0], lb[r+1][1], w0, w1,
                               q0, q1, y0, y1, hasY, (w0 | w1) != 0);
        float za = fmaf((float)hqa, c1q, c0);
        float sa = za * __builtin_amdgcn_rcpf(1.f + fabsf(za));
        SsA += sa; Ss2A = fmaf(sa, sa, Ss2A);
        float zb = fmaf((float)hqb, c1q, c0);
        float sb = zb * __builtin_amdgcn_rcpf(1.f + fabsf(zb));
        SsB += sb; Ss2B = fmaf(sb, sb, Ss2B);
    }
    int pidx = j * NPART + blockIdx.x * 2 + half;
    sS[pidx] = SsA + SsB; sS2[pidx] = Ss2A + Ss2B;
}

// R2: reduce softsign stats (f64), fold BN1, derive the two integer
// thresholds per column; lin_w binarize computed inline.
__global__ __launch_bounds__(256) void r2_sreduce(
        const float* __restrict__ sS, const float* __restrict__ sS2,
        const float* __restrict__ g1, const float* __restrict__ b1,
        const float* __restrict__ bn2c, const float* __restrict__ lw,
        u32* __restrict__ meta) {
    int j = blockIdx.x, tid = threadIdx.x;
    double s = 0.0, s2 = 0.0;
    for (int k = tid; k < NPART; k += 256) { s += (double)sS[j*NPART+k]; s2 += (double)sS2[j*NPART+k]; }
    for (int off = 32; off; off >>= 1) { s += __shfl_down(s, off, 64); s2 += __shfl_down(s2, off, 64); }
    __shared__ double ds_[4], ds2_[4];
    __shared__ float sd1, sd0;
    __shared__ u32 cnt[3];
    __shared__ u32 sfirst, slast;
    int lane = tid & 63, wave = tid >> 6;
    if (lane == 0) { ds_[wave] = s; ds2_[wave] = s2; }
    if (tid < 3) cnt[tid] = 0;
    __syncthreads();
    if (tid == 0) {
        double S = ds_[0] + ds_[1] + ds_[2] + ds_[3];
        double S2 = ds2_[0] + ds2_[1] + ds2_[2] + ds2_[3];
        double m1 = S / (double)BATCH;
        double v1 = S2 / (double)BATCH - m1 * m1;
        float rs = (float)(1.0 / sqrt(v1 + 1e-5));
        float d1 = rs * g1[j];
        float d0 = fmaf(-(float)m1, d1, b1[j]);
        sd1 = d1; sd0 = d0;
    }
    __syncthreads();
    float c1q = bn2c[j], c0 = bn2c[128 + j];
    float d1 = sd1, d0 = sd0;
    for (int hq = tid; hq < 481; hq += 256) {
        float z = fmaf((float)hq, c1q, c0);
        float sv = z * __builtin_amdgcn_rcpf(1.f + fabsf(z));
        float h1 = fmaf(sv, d1, d0);
        u32 hb2 = h1 > 0.f ? 2u : (h1 == 0.f ? 1u : 0u);
        atomicAdd(&cnt[hb2], 1u);
        if (hq == 0)   sfirst = hb2;
        if (hq == 480) slast  = hb2;
    }
    __syncthreads();
    if (tid == 0) {
        u32 n0 = cnt[0], n1 = cnt[1], n2 = cnt[2];
        u32 dec = (slast < sfirst) ? 1u : 0u;
        u32 A = dec ? n2 : n0;
        u32 B = A + n1;
        float w0 = lw[j], w1 = lw[DIM + j];
        u32 l0 = w0 > 0.f ? 2u : (w0 == 0.f ? 1u : 0u);
        u32 l1 = w1 > 0.f ? 2u : (w1 == 0.f ? 1u : 0u);
        meta[2*j]   = A | (B << 9) | (dec << 18);
        meta[2*j+1] = l0 | (l1 << 16);
    }
}

// K3: thread <-> row, chunked-register column loop, per-block stat partials
// to distinct addresses (no global atomics).
__global__ __launch_bounds__(256) void k3_out(
        const u64* __restrict__ xbits, const u64* __restrict__ wbits,
        const u32* __restrict__ meta, const u32* __restrict__ oacc,
        u32* __restrict__ oqbuf, u32* __restrict__ oP) {
    __shared__ u64 sq0[DIM], sq1[DIM], smw[DIM], sy0[DIM], sy1[DIM];
    int tid = threadIdx.x;
    for (int k = tid; k < DIM; k += 256) {
        sq0[k] = wbits[k*4+0]; sq1[k] = wbits[k*4+1];
        sy0[k] = wbits[k*4+2]; sy1[k] = wbits[k*4+3];
        smw[k] = (u64)meta[2*k] | ((u64)meta[2*k+1] << 32);
    }
    __syncthreads();
    size_t row = (size_t)blockIdx.x * 256 + tid;
    const ulonglong2* xb = (const ulonglong2*)xbits;
    ulonglong2 rp = xb[row*2], rz = xb[row*2+1];
    u64 p0 = rp.x, p1 = rp.y, z0 = rz.x, z1 = rz.y;
    u32 oq = 0;
    for (int c = 0; c < DIM; c += CH) {
        ulonglong2 A[CH/2], B[CH/2], Mw[CH/2];
        #pragma unroll
        for (int t = 0; t < CH/2; ++t) {
            A[t] = *(const ulonglong2*)&sq0[c + 2*t];
            B[t] = *(const ulonglong2*)&sq1[c + 2*t];
            Mw[t] = *(const ulonglong2*)&smw[c + 2*t];
        }
        #pragma unroll
        for (int t = 0; t < CH/2; ++t) {
            proc_col(p0, p1, A[t].x, B[t].x, Mw[t].x, oq);
            proc_col(p0, p1, A[t].y, B[t].y, Mw[t].y, oq);
        }
    }
    bool slow = (oacc[8] != 0) | ((z0 | z1) != 0);
    if (__any(slow)) {
        if (slow) {          // exact full recompute (expected ~2 rows/batch)
            oq = 0;
            for (int j = 0; j < DIM; ++j) {
                u64 y0 = sy0[j], y1 = sy1[j];
                u32 hq = hq_from_bits(p0, p1, z0, z1, sq0[j], sq1[j], y0, y1,
                                      (y0 | y1) != 0, (z0 | z1) != 0);
                u64 mw = smw[j];
                u32 m = (u32)mw, lw = (u32)(mw >> 32);
                u32 ge = (u32)(hq >= (m & 511u)) + (u32)(hq >= ((m >> 9) & 511u));
                oq += ((m & (1u << 18)) ? 2u - ge : ge) * lw;
            }
        }
    }
    oqbuf[row] = oq;
    u32 o0 = oq & 0xffffu, o1 = oq >> 16;
    u32 a = o0, b = o1, c2 = o0 * o0, d2 = o1 * o1;
    for (int off = 32; off; off >>= 1) {
        a += __shfl_down(a, off, 64);  b += __shfl_down(b, off, 64);
        c2 += __shfl_down(c2, off, 64); d2 += __shfl_down(d2, off, 64);
    }
    __shared__ u32 r0_[4], r1_[4], r2_[4], r3_[4];
    int lane = tid & 63, wv = tid >> 6;
    if (lane == 0) { r0_[wv] = a; r1_[wv] = b; r2_[wv] = c2; r3_[wv] = d2; }
    __syncthreads();
    if (tid == 0) {
        u32* dst = oP + (size_t)blockIdx.x * 4;
        dst[0] = r0_[0] + r0_[1] + r0_[2] + r0_[3];
        dst[1] = r1_[0] + r1_[1] + r1_[2] + r1_[3];
        dst[2] = r2_[0] + r2_[1] + r2_[2] + r2_[3];
        dst[3] = r3_[0] + r3_[1] + r3_[2] + r3_[3];
    }
}

// K4: each block redundantly reduces the 16KB oP partials (exact integers,
// f64 finalize), then normalizes its 256 rows + 2-class log_softmax.
__global__ __launch_bounds__(256) void k4_final(
        const u32* __restrict__ oqbuf, const u32* __restrict__ oP,
        float* __restrict__ out) {
    int tid = threadIdx.x;
    u64 a = 0, b = 0, c2 = 0, d2 = 0;
    for (int k = tid; k < NBLK3; k += 256) {
        uint4 p = ((const uint4*)oP)[k];
        a += p.x; b += p.y; c2 += p.z; d2 += p.w;
    }
    for (int off = 32; off; off >>= 1) {
        a += __shfl_down(a, off, 64);  b += __shfl_down(b, off, 64);
        c2 += __shfl_down(c2, off, 64); d2 += __shfl_down(d2, off, 64);
    }
    __shared__ u64 s0_[4], s1_[4], s2_[4], s3_[4];
    __shared__ float sfin[4];
    int lane = tid & 63, wv = tid >> 6;
    if (lane == 0) { s0_[wv] = a; s1_[wv] = b; s2_[wv] = c2; s3_[wv] = d2; }
    __syncthreads();
    if (tid < 2) {
        u64 S  = (tid == 0) ? s0_[0]+s0_[1]+s0_[2]+s0_[3] : s1_[0]+s1_[1]+s1_[2]+s1_[3];
        u64 S2 = (tid == 0) ? s2_[0]+s2_[1]+s2_[2]+s2_[3] : s3_[0]+s3_[1]+s3_[2]+s3_[3];
        double av = (double)S * 0.25 / (double)BATCH;
        double e2 = (double)S2 * 0.0625 / (double)BATCH;
        double vo = e2 - av * av;
        sfin[tid]     = (float)av;
        sfin[2 + tid] = (float)(1.0 / sqrt(vo + 1e-5));
    }
    __syncthreads();
    size_t row = (size_t)blockIdx.x * 256 + tid;
    u32 v = oqbuf[row];
    float o0 = ((float)(v & 0xffffu) * 0.25f - sfin[0]) * sfin[2];
    float o1 = ((float)(v >> 16)     * 0.25f - sfin[1]) * sfin[3];
    float m = fmaxf(o0, o1);
    float l0 = o0 - m, l1 = o1 - m;
    float ls = logf(expf(l0) + expf(l1));
    ((float2*)out)[row] = make_float2(l0 - ls, l1 - ls);
}

extern "C" void kernel_launch(void* const* d_in, const int* in_sizes, int n_in,
                              void* d_out, int out_size, void* d_ws, size_t ws_size,
                              hipStream_t stream) {
    const float* x  = (const float*)d_in[0];
    const float* cw = (const float*)d_in[1];
    const float* g2 = (const float*)d_in[2];
    const float* b2 = (const float*)d_in[3];
    const float* g1 = (const float*)d_in[4];
    const float* b1 = (const float*)d_in[5];
    const float* lw = (const float*)d_in[6];
    // d_in[7] (lin_b) cancels through the final no-affine batchnorm
    float* out = (float*)d_out;
    if (ws_size < (size_t)WS_TOTAL) return;   // fail loudly via poisoned d_out

    char* ws = (char*)d_ws;
    u64* xbits = (u64*)(ws + WS_XBITS);
    u64* wbits = (u64*)(ws + WS_WBITS);
    u32* meta  = (u32*)(ws + WS_META);
    u32* hP    = (u32*)(ws + WS_HS);
    u32* h2P   = (u32*)(ws + WS_HS2);
    float* sP  = (float*)(ws + WS_SS);
    float* s2P = (float*)(ws + WS_SS2);
    float* bn2c = (float*)(ws + WS_BN2C);
    u32* oqbuf = (u32*)(ws + WS_OQ);
    u32* oacc  = (u32*)(ws + WS_OACC);
    u32* oP    = (u32*)(ws + WS_OP);

    k1_pack_hstats<<<NBLK1, 256, 0, stream>>>(x, cw, wbits, oacc, xbits, hP, h2P);
    r1_hreduce    <<<DIM, 256, 0, stream>>>(hP, h2P, g2, b2, bn2c);
    k2_sstats     <<<NBLK1, 256, 0, stream>>>(xbits, wbits, bn2c, sP, s2P);
    r2_sreduce    <<<DIM, 256, 0, stream>>>(sP, s2P, g1, b1, bn2c, lw, meta);
    k3_out        <<<NBLK3, 256, 0, stream>>>(xbits, wbits, meta, oacc, oqbuf, oP);
    k4_final      <<<NBLK3, 256, 0, stream>>>(oqbuf, oP, out);
}